// Round 14
// baseline (286.546 us; speedup 1.0000x reference)
//
#include <hip/hip_runtime.h>

#define N_USER 50000
#define N_ITEM 50000
#define N_EDGE 800000
#define D 128
#define NTOT   100000          // combined dst space: [0,50K)=items, [50K,100K)=users
#define NE2    1600000         // both directions' edges
#define BKT_SH 9               // 512 dsts per bucket
#define NBKT   196             // ceil(NTOT / 512)
#define CAP    12288           // LDS csr staging cap (bucket mean 8192, sigma ~90)

// Slice-major feature tables: T[slice][node][16 dims], slice = dim>>4.
// One slice = 50000*16 u16 = 1.6MB -> fits per-XCD L2 (2 tables = 3.2MB < 4MB).
#define NSLICE 8
#define SLICE_STRIDE (50000 * 16)   // u16 elements per slice

typedef __attribute__((ext_vector_type(8))) short     bf16x8;
typedef __attribute__((ext_vector_type(4))) float     f32x4;
typedef __attribute__((ext_vector_type(4))) unsigned short ushortx4;
typedef __attribute__((ext_vector_type(8))) unsigned short ushortx8;

__device__ __forceinline__ unsigned short f2bf(float f) {
    unsigned int u = __float_as_uint(f);
    unsigned int r = (u + 0x7fffu + ((u >> 16) & 1u)) >> 16;   // RNE
    return (unsigned short)r;
}
__device__ __forceinline__ float bf2f(unsigned short b) {
    return __uint_as_float(((unsigned int)b) << 16);
}

// ---------------------------------------------------------------------------
// MEGA kernel (block-range roles, all 256 thr). pack/packW/count independent.
// Pack now writes SLICE-MAJOR tables.
// ---------------------------------------------------------------------------
#define PACKA_BLOCKS 12500
#define PACKW_BLOCKS 32
#define CNT_BLOCKS   391   // ceil(NE2 / 4096)

__global__ __launch_bounds__(256) void mega3_kernel(
    const float* __restrict__ user_emb, const int* __restrict__ user_ids,
    const float* __restrict__ item_x,
    const int* __restrict__ edge_ui, const int* __restrict__ edge_iu,
    const float* __restrict__ Wl_ui, const float* __restrict__ Wr_ui,
    const float* __restrict__ Wl_iu, const float* __restrict__ Wr_iu,
    unsigned short* T_user, unsigned short* T_item,
    unsigned short* WfragUI, unsigned short* WfragIU,
    int* __restrict__ gcnt)
{
    const int b = blockIdx.x;
    const int tid = threadIdx.x;

    if (b < PACKA_BLOCKS) {
        int gid = b * 256 + tid;
        int row = gid >> 5;
        int c0 = (gid & 31) << 2;            // dims c0..c0+3 (within one 16-dim slice)
        const float* src;
        unsigned short* T;
        int trow;
        if (row < N_USER) { src = user_emb + (size_t)user_ids[row] * D; T = T_user; trow = row; }
        else              { src = item_x + (size_t)(row - N_USER) * D;  T = T_item; trow = row - N_USER; }
        const float4 v = *reinterpret_cast<const float4*>(src + c0);
        ushortx4 o;
        o.x = f2bf(v.x); o.y = f2bf(v.y); o.z = f2bf(v.z); o.w = f2bf(v.w);
        unsigned short* dst = T + (size_t)(c0 >> 4) * SLICE_STRIDE + (size_t)trow * 16 + (c0 & 15);
        *reinterpret_cast<ushortx4*>(dst) = o;
    } else if (b < PACKA_BLOCKS + PACKW_BLOCKS) {
        int id = (b - PACKA_BLOCKS) * 256 + tid;   // [0, 8192)
        const float *Wl, *Wr;
        unsigned short* Wf;
        if (id < 4096) { Wl = Wl_ui; Wr = Wr_ui; Wf = WfragUI; }
        else { id -= 4096; Wl = Wl_iu; Wr = Wr_iu; Wf = WfragIU; }
        int lane = id & 63;
        int c    = (id >> 6) & 7;
        int ks   = id >> 9;
        int col  = c * 16 + (lane & 15);
        int k0   = ks * 32 + (lane >> 4) * 8;
        ushortx8 o;
#pragma unroll
        for (int i = 0; i < 8; ++i) {
            int k = k0 + i;
            float f = (k < D) ? Wl[(size_t)k * D + col] : Wr[(size_t)(k - D) * D + col];
            o[i] = f2bf(f);
        }
        *reinterpret_cast<ushortx8*>(Wf + (size_t)id * 8) = o;
    } else {
        __shared__ int bcnt[NBKT];
        for (int i = tid; i < NBKT; i += 256) bcnt[i] = 0;
        __syncthreads();
        int e0 = (b - PACKA_BLOCKS - PACKW_BLOCKS) * 4096;
#pragma unroll
        for (int j = 0; j < 16; ++j) {
            int e = e0 + j * 256 + tid;
            if (e < NE2) {
                int d = (e < N_EDGE) ? edge_ui[N_EDGE + e]
                                     : (N_ITEM + edge_iu[N_EDGE + (e - N_EDGE)]);
                atomicAdd(&bcnt[d >> BKT_SH], 1);
            }
        }
        __syncthreads();
        for (int i = tid; i < NBKT; i += 256)
            if (bcnt[i]) atomicAdd(&gcnt[i], bcnt[i]);
    }
}

// ---------------------------------------------------------------------------
// Scan 196 bucket counts -> bucket bases; init bucket cursors.
// ---------------------------------------------------------------------------
__global__ __launch_bounds__(256) void bucketscan_kernel(
    const int* __restrict__ gcnt, int* __restrict__ bbase, int* __restrict__ bcur)
{
    __shared__ int s[256];
    int tid = threadIdx.x;
    int v = (tid < NBKT) ? gcnt[tid] : 0;
    s[tid] = v;
    __syncthreads();
    for (int d = 1; d < 256; d <<= 1) {
        int t = (tid >= d) ? s[tid - d] : 0;
        __syncthreads();
        s[tid] += t;
        __syncthreads();
    }
    if (tid < NBKT) {
        int base = s[tid] - v;     // exclusive
        bbase[tid] = base;
        bcur[tid]  = base;
    }
    if (tid == NBKT - 1) bbase[NBKT] = s[tid];
}

// ---------------------------------------------------------------------------
// Scatter records into bucket-segmented array. Record = src16 | dstlow9<<16.
// ---------------------------------------------------------------------------
#define B2_BLOCKS 196   // ceil(NE2 / 8192)

__global__ __launch_bounds__(1024) void scatter_records_kernel(
    const int* __restrict__ edge_ui, const int* __restrict__ edge_iu,
    int* __restrict__ bcur, unsigned int* __restrict__ records)
{
    __shared__ int bcnt[NBKT];
    __shared__ int bpos[NBKT];
    const int tid = threadIdx.x;
    for (int i = tid; i < NBKT; i += 1024) bcnt[i] = 0;
    __syncthreads();

    const int e0 = blockIdx.x * 8192;
    unsigned int rec[8];
    int bkt[8], rnk[8];
#pragma unroll
    for (int j = 0; j < 8; ++j) {
        int e = e0 + j * 1024 + tid;
        bkt[j] = -1;
        if (e < NE2) {
            int s, d;
            if (e < N_EDGE) { s = edge_ui[e]; d = edge_ui[N_EDGE + e]; }
            else { int f = e - N_EDGE; s = edge_iu[f]; d = N_ITEM + edge_iu[N_EDGE + f]; }
            bkt[j] = d >> BKT_SH;
            rec[j] = (unsigned int)s | ((unsigned int)(d & 511) << 16);
            rnk[j] = atomicAdd(&bcnt[bkt[j]], 1);
        }
    }
    __syncthreads();
    for (int i = tid; i < NBKT; i += 1024) {
        int c = bcnt[i];
        bpos[i] = c ? atomicAdd(&bcur[i], c) : 0;
    }
    __syncthreads();
#pragma unroll
    for (int j = 0; j < 8; ++j) {
        if (bkt[j] >= 0) records[bpos[bkt[j]] + rnk[j]] = rec[j];
    }
}

// ---------------------------------------------------------------------------
// Per-bucket CSR build: LDS counting-sort by dst within the bucket; emits off[].
// ---------------------------------------------------------------------------
__global__ __launch_bounds__(1024) void csr_build_kernel(
    const unsigned int* __restrict__ records, const int* __restrict__ bbase,
    unsigned short* __restrict__ csr, int* __restrict__ off)
{
    __shared__ int dcnt[512];
    __shared__ int sa[512], sb[512];
    __shared__ int dcur[512];
    __shared__ unsigned short stage[CAP];

    const int b    = blockIdx.x;
    const int tid  = threadIdx.x;
    const int base = bbase[b];
    const int nb   = bbase[b + 1] - base;

    if (tid < 512) dcnt[tid] = 0;
    __syncthreads();

    for (int i = tid; i < nb; i += 1024)
        atomicAdd(&dcnt[records[base + i] >> 16], 1);
    __syncthreads();

    int* pa = sa; int* pb = sb;
    if (tid < 512) pa[tid] = dcnt[tid];
    __syncthreads();
    for (int d = 1; d < 512; d <<= 1) {
        if (tid < 512) pb[tid] = pa[tid] + ((tid >= d) ? pa[tid - d] : 0);
        __syncthreads();
        int* t = pa; pa = pb; pb = t;
    }
    if (tid < 512) {
        int excl = pa[tid] - dcnt[tid];
        dcur[tid] = excl;
        int dst = b * 512 + tid;
        if (dst < NTOT) off[dst] = base + excl;
    }
    if (b == NBKT - 1 && tid == 0) off[NTOT] = NE2;
    __syncthreads();

    if (nb <= CAP) {
        for (int i = tid; i < nb; i += 1024) {
            unsigned int r = records[base + i];
            int p = atomicAdd(&dcur[r >> 16], 1);
            stage[p] = (unsigned short)r;
        }
        __syncthreads();
        for (int i = tid; i < nb; i += 1024) csr[base + i] = stage[i];
    } else {
        for (int i = tid; i < nb; i += 1024) {
            unsigned int r = records[base + i];
            int p = atomicAdd(&dcur[r >> 16], 1);
            csr[base + p] = (unsigned short)r;
        }
    }
}

// ---------------------------------------------------------------------------
// Aggregate (mean), XCD-SLICED: block = (slice, side, 4 rows), 256 thr.
// slice = blockIdx & 7 -> XCD (empirical %8 round-robin; perf-only).
// Wave = one dst row: lane layout eo=lane>>3 (edge slot 0..7), dl=lane&7
// (dims 2dl,2dl+1 of the 16-dim slice). One gather instruction serves 8
// edges (8 x 32B segments); 4-deep unroll = 32 edges in flight per wave.
// Merge across edge slots via 3x shfl_xor; eo==0 lanes write 32B.
// ---------------------------------------------------------------------------
__global__ __launch_bounds__(256) void agg4_kernel(
    const unsigned short* __restrict__ T_user, const unsigned short* __restrict__ T_item,
    const int* __restrict__ off, const unsigned short* __restrict__ csr,
    unsigned short* __restrict__ dout_u16)
{
    const int b    = blockIdx.x;            // [0, 200000)
    const int sl   = b & 7;                 // slice -> XCD
    int rest       = b >> 3;                // [0, 25000)
    const int side = (rest >= 12500) ? 1 : 0;   // 0 = item dst, 1 = user dst
    if (side) rest -= 12500;
    const int wave = threadIdx.x >> 6;
    const int lane = threadIdx.x & 63;
    const int r    = rest * 4 + wave;       // side-local row [0, 50000)
    const int eo   = lane >> 3;
    const int dl   = lane & 7;

    const unsigned short* Tg = (side ? T_item : T_user) + (size_t)sl * SLICE_STRIDE;
    const int dr = side ? (N_ITEM + r) : r;
    unsigned short* outp = side ? (dout_u16 + (size_t)r * 256)
                                : (dout_u16 + (size_t)(N_USER + r) * 256);

    const int o0 = off[dr], o1 = off[dr + 1];
    const int deg = o1 - o0;
    const int dimoff = dl * 2;
    float ax = 0.f, ay = 0.f;

    for (int i = o0; i < o1; i += 32) {
#pragma unroll
        for (int k = 0; k < 4; ++k) {
            int e = i + k * 8 + eo;
            if (e < o1) {
                int s = csr[e];
                unsigned int w = *reinterpret_cast<const unsigned int*>(
                    Tg + (size_t)s * 16 + dimoff);
                ax += bf2f((unsigned short)w);
                ay += bf2f((unsigned short)(w >> 16));
            }
        }
    }

    // reduce across the 8 edge slots
    ax += __shfl_xor(ax, 8);  ay += __shfl_xor(ay, 8);
    ax += __shfl_xor(ax, 16); ay += __shfl_xor(ay, 16);
    ax += __shfl_xor(ax, 32); ay += __shfl_xor(ay, 32);

    float sc = (deg > 0) ? 1.0f / (float)deg : 0.0f;
    if (eo == 0) {
        unsigned int outw = (unsigned int)f2bf(ax * sc) | ((unsigned int)f2bf(ay * sc) << 16);
        *reinterpret_cast<unsigned int*>(outp + sl * 16 + dimoff) = outw;
    }
}

// ---------------------------------------------------------------------------
// MFMA finish, head from d_out (stride 256, in-place row-aliased), tail from
// SLICE-MAJOR self table: dims D0 = (ks-4)*32 + kg*8 live contiguously at
// slice D0>>4, in-slice offset D0&15.
// ---------------------------------------------------------------------------
#define NB_FIN 782   // ceil(50000/64)

__global__ __launch_bounds__(256) void finish2c_kernel(
    unsigned short* dout_u16,
    const unsigned short* __restrict__ T_user, const unsigned short* __restrict__ T_item,
    const unsigned short* __restrict__ WfragUI, const unsigned short* __restrict__ WfragIU,
    const float* __restrict__ b_ui, const float* __restrict__ b_iu)
{
    const int b = blockIdx.x;
    const unsigned short *headBase, *Ts, *Wfrag;
    const float* bias;
    float* outp;
    int rowBase;
    if (b < NB_FIN) {
        headBase = dout_u16 + (size_t)N_USER * 256;
        Ts = T_item; Wfrag = WfragUI; bias = b_ui;
        outp = reinterpret_cast<float*>(dout_u16) + (size_t)N_USER * 128;
        rowBase = b * 64;
    } else {
        headBase = dout_u16;
        Ts = T_user; Wfrag = WfragIU; bias = b_iu;
        outp = reinterpret_cast<float*>(dout_u16);
        rowBase = (b - NB_FIN) * 64;
    }

    const int tid  = threadIdx.x;
    const int wave = tid >> 6;
    const int lane = tid & 63;
    const int kg   = lane >> 4;
    rowBase += wave * 16;

    int arow = rowBase + (lane & 15);
    int arow_c = (arow < 50000) ? arow : 49999;
    const unsigned short* head_ptr = headBase + (size_t)arow_c * 256 + kg * 8;

    f32x4 acc[8];
#pragma unroll
    for (int c = 0; c < 8; ++c) acc[c] = (f32x4){0.f, 0.f, 0.f, 0.f};

#pragma unroll
    for (int ks = 0; ks < 8; ++ks) {
        bf16x8 a;
        if (ks < 4) {
            a = *reinterpret_cast<const bf16x8*>(head_ptr + ks * 32);       // agg (Wl)
        } else {
            const int D0 = (ks - 4) * 32 + kg * 8;                          // self (Wr)
            a = *reinterpret_cast<const bf16x8*>(
                Ts + (size_t)(D0 >> 4) * SLICE_STRIDE + (size_t)arow_c * 16 + (D0 & 15));
        }
        const unsigned short* bptr = Wfrag + ((size_t)(ks * 8) * 64 + lane) * 8;
#pragma unroll
        for (int c = 0; c < 8; ++c) {
            bf16x8 bb = *reinterpret_cast<const bf16x8*>(bptr + (size_t)c * 512);
            acc[c] = __builtin_amdgcn_mfma_f32_16x16x32_bf16(a, bb, acc[c], 0, 0, 0);
        }
    }

    const int orow0 = rowBase + kg * 4;
    const int ocol  = lane & 15;
#pragma unroll
    for (int c = 0; c < 8; ++c) {
        float bv = bias[c * 16 + ocol];
#pragma unroll
        for (int r = 0; r < 4; ++r) {
            int row = orow0 + r;
            if (row < 50000) outp[(size_t)row * 128 + c * 16 + ocol] = acc[c][r] + bv;
        }
    }
}

// ---------------------------------------------------------------------------
extern "C" void kernel_launch(void* const* d_in, const int* in_sizes, int n_in,
                              void* d_out, int out_size, void* d_ws, size_t ws_size,
                              hipStream_t stream) {
    const int*   user_ids = (const int*)d_in[0];
    const float* item_x   = (const float*)d_in[1];
    const int*   edge_ui  = (const int*)d_in[2];
    const int*   edge_iu  = (const int*)d_in[3];
    const float* user_emb = (const float*)d_in[4];
    const float* W_l_ui   = (const float*)d_in[5];
    const float* W_r_ui   = (const float*)d_in[6];
    const float* b_ui     = (const float*)d_in[7];
    const float* W_l_iu   = (const float*)d_in[8];
    const float* W_r_iu   = (const float*)d_in[9];
    const float* b_iu     = (const float*)d_in[10];

    unsigned short* dout_u16 = (unsigned short*)d_out;

    // Workspace (16B-aligned blocks first)
    unsigned short* WfragUI = (unsigned short*)d_ws;            // 32768 u16
    unsigned short* WfragIU = WfragUI + 32768;                  // 32768 u16
    unsigned short* T_user  = WfragIU + 32768;                  // slice-major, 12.8MB
    unsigned short* T_item  = T_user + (size_t)NSLICE * SLICE_STRIDE;   // 12.8MB
    unsigned int*   records = (unsigned int*)(T_item + (size_t)NSLICE * SLICE_STRIDE);  // 6.4MB
    unsigned short* csr     = (unsigned short*)(records + NE2); // 3.2MB
    int* gcnt  = (int*)(csr + NE2);                             // NBKT
    int* bbase = gcnt + NBKT;                                   // NBKT+1
    int* bcur  = bbase + NBKT + 1;                              // NBKT
    int* off   = bcur + NBKT;                                   // NTOT+1

    hipMemsetAsync(gcnt, 0, NBKT * sizeof(int), stream);

    mega3_kernel<<<PACKA_BLOCKS + PACKW_BLOCKS + CNT_BLOCKS, 256, 0, stream>>>(
        user_emb, user_ids, item_x, edge_ui, edge_iu,
        W_l_ui, W_r_ui, W_l_iu, W_r_iu,
        T_user, T_item, WfragUI, WfragIU, gcnt);
    bucketscan_kernel<<<1, 256, 0, stream>>>(gcnt, bbase, bcur);
    scatter_records_kernel<<<B2_BLOCKS, 1024, 0, stream>>>(edge_ui, edge_iu, bcur, records);
    csr_build_kernel<<<NBKT, 1024, 0, stream>>>(records, bbase, csr, off);

    agg4_kernel<<<2 * 12500 * NSLICE, 256, 0, stream>>>(T_user, T_item, off, csr, dout_u16);
    finish2c_kernel<<<2 * NB_FIN, 256, 0, stream>>>(
        dout_u16, T_user, T_item, WfragUI, WfragIU, b_ui, b_iu);
}

// Round 15
// 146.883 us; speedup vs baseline: 1.9508x; 1.9508x over previous
//
#include <hip/hip_runtime.h>

#define N_USER 50000
#define N_ITEM 50000
#define N_EDGE 800000
#define D 128
#define NTOT   100000          // combined dst space: [0,50K)=items, [50K,100K)=users
#define NE2    1600000         // both directions' edges
#define BKT_SH 9               // 512 dsts per bucket
#define NBKT   196             // ceil(NTOT / 512)
#define CAP    12288           // LDS csr staging cap (bucket mean 8192, sigma ~90)

typedef __attribute__((ext_vector_type(8))) short     bf16x8;
typedef __attribute__((ext_vector_type(4))) float     f32x4;
typedef __attribute__((ext_vector_type(4))) unsigned short ushortx4;
typedef __attribute__((ext_vector_type(8))) unsigned short ushortx8;

__device__ __forceinline__ unsigned short f2bf(float f) {
    unsigned int u = __float_as_uint(f);
    unsigned int r = (u + 0x7fffu + ((u >> 16) & 1u)) >> 16;   // RNE
    return (unsigned short)r;
}
__device__ __forceinline__ float bf2f(unsigned short b) {
    return __uint_as_float(((unsigned int)b) << 16);
}

// ---------------------------------------------------------------------------
// MEGA kernel (block-range roles, all 256 thr). pack/packW/count are mutually
// independent -> count's latency hides under pack's copy traffic.
// ---------------------------------------------------------------------------
#define PACKA_BLOCKS 12500
#define PACKW_BLOCKS 32
#define CNT_BLOCKS   391   // ceil(NE2 / 4096)

__global__ __launch_bounds__(256) void mega3_kernel(
    const float* __restrict__ user_emb, const int* __restrict__ user_ids,
    const float* __restrict__ item_x,
    const int* __restrict__ edge_ui, const int* __restrict__ edge_iu,
    const float* __restrict__ Wl_ui, const float* __restrict__ Wr_ui,
    const float* __restrict__ Wl_iu, const float* __restrict__ Wr_iu,
    unsigned short* T_user, unsigned short* T_item,
    unsigned short* WfragUI, unsigned short* WfragIU,
    int* __restrict__ gcnt)
{
    const int b = blockIdx.x;
    const int tid = threadIdx.x;

    if (b < PACKA_BLOCKS) {
        int gid = b * 256 + tid;
        int row = gid >> 5;
        int c = (gid & 31) << 2;
        const float* src;
        unsigned short* dst;
        if (row < N_USER) {
            src = user_emb + (size_t)user_ids[row] * D;
            dst = T_user + (size_t)row * 128;
        } else {
            int r = row - N_USER;
            src = item_x + (size_t)r * D;
            dst = T_item + (size_t)r * 128;
        }
        const float4 v = *reinterpret_cast<const float4*>(src + c);
        ushortx4 o;
        o.x = f2bf(v.x); o.y = f2bf(v.y); o.z = f2bf(v.z); o.w = f2bf(v.w);
        *reinterpret_cast<ushortx4*>(dst + c) = o;
    } else if (b < PACKA_BLOCKS + PACKW_BLOCKS) {
        int id = (b - PACKA_BLOCKS) * 256 + tid;   // [0, 8192)
        const float *Wl, *Wr;
        unsigned short* Wf;
        if (id < 4096) { Wl = Wl_ui; Wr = Wr_ui; Wf = WfragUI; }
        else { id -= 4096; Wl = Wl_iu; Wr = Wr_iu; Wf = WfragIU; }
        int lane = id & 63;
        int c    = (id >> 6) & 7;
        int ks   = id >> 9;
        int col  = c * 16 + (lane & 15);
        int k0   = ks * 32 + (lane >> 4) * 8;
        ushortx8 o;
#pragma unroll
        for (int i = 0; i < 8; ++i) {
            int k = k0 + i;
            float f = (k < D) ? Wl[(size_t)k * D + col] : Wr[(size_t)(k - D) * D + col];
            o[i] = f2bf(f);
        }
        *reinterpret_cast<ushortx8*>(Wf + (size_t)id * 8) = o;
    } else {
        __shared__ int bcnt[NBKT];
        for (int i = tid; i < NBKT; i += 256) bcnt[i] = 0;
        __syncthreads();
        int e0 = (b - PACKA_BLOCKS - PACKW_BLOCKS) * 4096;
#pragma unroll
        for (int j = 0; j < 16; ++j) {
            int e = e0 + j * 256 + tid;
            if (e < NE2) {
                int d = (e < N_EDGE) ? edge_ui[N_EDGE + e]
                                     : (N_ITEM + edge_iu[N_EDGE + (e - N_EDGE)]);
                atomicAdd(&bcnt[d >> BKT_SH], 1);
            }
        }
        __syncthreads();
        for (int i = tid; i < NBKT; i += 256)
            if (bcnt[i]) atomicAdd(&gcnt[i], bcnt[i]);
    }
}

// ---------------------------------------------------------------------------
// Scan 196 bucket counts -> bucket bases; init bucket cursors.
// ---------------------------------------------------------------------------
__global__ __launch_bounds__(256) void bucketscan_kernel(
    const int* __restrict__ gcnt, int* __restrict__ bbase, int* __restrict__ bcur)
{
    __shared__ int s[256];
    int tid = threadIdx.x;
    int v = (tid < NBKT) ? gcnt[tid] : 0;
    s[tid] = v;
    __syncthreads();
    for (int d = 1; d < 256; d <<= 1) {
        int t = (tid >= d) ? s[tid - d] : 0;
        __syncthreads();
        s[tid] += t;
        __syncthreads();
    }
    if (tid < NBKT) {
        int base = s[tid] - v;     // exclusive
        bbase[tid] = base;
        bcur[tid]  = base;
    }
    if (tid == NBKT - 1) bbase[NBKT] = s[tid];
}

// ---------------------------------------------------------------------------
// Scatter records into bucket-segmented array. Record = src16 | dstlow9<<16.
// Rank captured from the pass-1 count atomic; final writes atomic-free.
// ---------------------------------------------------------------------------
#define B2_BLOCKS 196   // ceil(NE2 / 8192)

__global__ __launch_bounds__(1024) void scatter_records_kernel(
    const int* __restrict__ edge_ui, const int* __restrict__ edge_iu,
    int* __restrict__ bcur, unsigned int* __restrict__ records)
{
    __shared__ int bcnt[NBKT];
    __shared__ int bpos[NBKT];
    const int tid = threadIdx.x;
    for (int i = tid; i < NBKT; i += 1024) bcnt[i] = 0;
    __syncthreads();

    const int e0 = blockIdx.x * 8192;
    unsigned int rec[8];
    int bkt[8], rnk[8];
#pragma unroll
    for (int j = 0; j < 8; ++j) {
        int e = e0 + j * 1024 + tid;
        bkt[j] = -1;
        if (e < NE2) {
            int s, d;
            if (e < N_EDGE) { s = edge_ui[e]; d = edge_ui[N_EDGE + e]; }
            else { int f = e - N_EDGE; s = edge_iu[f]; d = N_ITEM + edge_iu[N_EDGE + f]; }
            bkt[j] = d >> BKT_SH;
            rec[j] = (unsigned int)s | ((unsigned int)(d & 511) << 16);
            rnk[j] = atomicAdd(&bcnt[bkt[j]], 1);
        }
    }
    __syncthreads();
    for (int i = tid; i < NBKT; i += 1024) {
        int c = bcnt[i];
        bpos[i] = c ? atomicAdd(&bcur[i], c) : 0;
    }
    __syncthreads();
#pragma unroll
    for (int j = 0; j < 8; ++j) {
        if (bkt[j] >= 0) records[bpos[bkt[j]] + rnk[j]] = rec[j];
    }
}

// ---------------------------------------------------------------------------
// Per-bucket CSR build: LDS counting-sort by dst within the bucket; emits off[].
// ---------------------------------------------------------------------------
__global__ __launch_bounds__(1024) void csr_build_kernel(
    const unsigned int* __restrict__ records, const int* __restrict__ bbase,
    unsigned short* __restrict__ csr, int* __restrict__ off)
{
    __shared__ int dcnt[512];
    __shared__ int sa[512], sb[512];
    __shared__ int dcur[512];
    __shared__ unsigned short stage[CAP];

    const int b    = blockIdx.x;
    const int tid  = threadIdx.x;
    const int base = bbase[b];
    const int nb   = bbase[b + 1] - base;

    if (tid < 512) dcnt[tid] = 0;
    __syncthreads();

    for (int i = tid; i < nb; i += 1024)
        atomicAdd(&dcnt[records[base + i] >> 16], 1);
    __syncthreads();

    int* pa = sa; int* pb = sb;
    if (tid < 512) pa[tid] = dcnt[tid];
    __syncthreads();
    for (int d = 1; d < 512; d <<= 1) {
        if (tid < 512) pb[tid] = pa[tid] + ((tid >= d) ? pa[tid - d] : 0);
        __syncthreads();
        int* t = pa; pa = pb; pb = t;
    }
    if (tid < 512) {
        int excl = pa[tid] - dcnt[tid];
        dcur[tid] = excl;
        int dst = b * 512 + tid;
        if (dst < NTOT) off[dst] = base + excl;
    }
    if (b == NBKT - 1 && tid == 0) off[NTOT] = NE2;
    __syncthreads();

    if (nb <= CAP) {
        for (int i = tid; i < nb; i += 1024) {
            unsigned int r = records[base + i];
            int p = atomicAdd(&dcur[r >> 16], 1);
            stage[p] = (unsigned short)r;
        }
        __syncthreads();
        for (int i = tid; i < nb; i += 1024) csr[base + i] = stage[i];
    } else {
        for (int i = tid; i < nb; i += 1024) {
            unsigned int r = records[base + i];
            int p = atomicAdd(&dcur[r >> 16], 1);
            csr[base + p] = (unsigned short)r;
        }
    }
}

// ---------------------------------------------------------------------------
// Aggregate (mean), 16-deep unrolled gather: 256 thr = 4 free-running waves,
// one wave per dst row, lane owns dims [2l,2l+1], 16 gathers in flight.
// Writes bf16 mean into d_out head halves (stride 256).
// ---------------------------------------------------------------------------
__global__ __launch_bounds__(256) void agg2c_kernel(
    const unsigned short* __restrict__ T_user, const unsigned short* __restrict__ T_item,
    const int* __restrict__ off, const unsigned short* __restrict__ csr,
    unsigned short* __restrict__ dout_u16)
{
    int r = (blockIdx.x * blockDim.x + threadIdx.x) >> 6;
    if (r >= NTOT) return;
    const int lane = threadIdx.x & 63;
    const unsigned short* Tg;
    unsigned short* outp;
    if (r < N_ITEM) { Tg = T_user; outp = dout_u16 + (size_t)(N_USER + r) * 256; }
    else            { Tg = T_item; outp = dout_u16 + (size_t)(r - N_ITEM) * 256; }

    const int o0 = off[r], o1 = off[r + 1];
    const int co = lane * 2;
    float ax = 0.f, ay = 0.f;
    int i = o0;
    for (; i + 15 < o1; i += 16) {
        int s[16];
#pragma unroll
        for (int p = 0; p < 16; ++p) s[p] = csr[i + p];
        unsigned int w[16];
#pragma unroll
        for (int p = 0; p < 16; ++p)
            w[p] = *reinterpret_cast<const unsigned int*>(Tg + (size_t)s[p] * 128 + co);
#pragma unroll
        for (int p = 0; p < 16; ++p) {
            ax += bf2f((unsigned short)w[p]);
            ay += bf2f((unsigned short)(w[p] >> 16));
        }
    }
    for (; i + 7 < o1; i += 8) {
        int s0 = csr[i],     s1 = csr[i + 1], s2 = csr[i + 2], s3 = csr[i + 3];
        int s4 = csr[i + 4], s5 = csr[i + 5], s6 = csr[i + 6], s7 = csr[i + 7];
        unsigned int w0 = *reinterpret_cast<const unsigned int*>(Tg + (size_t)s0 * 128 + co);
        unsigned int w1 = *reinterpret_cast<const unsigned int*>(Tg + (size_t)s1 * 128 + co);
        unsigned int w2 = *reinterpret_cast<const unsigned int*>(Tg + (size_t)s2 * 128 + co);
        unsigned int w3 = *reinterpret_cast<const unsigned int*>(Tg + (size_t)s3 * 128 + co);
        unsigned int w4 = *reinterpret_cast<const unsigned int*>(Tg + (size_t)s4 * 128 + co);
        unsigned int w5 = *reinterpret_cast<const unsigned int*>(Tg + (size_t)s5 * 128 + co);
        unsigned int w6 = *reinterpret_cast<const unsigned int*>(Tg + (size_t)s6 * 128 + co);
        unsigned int w7 = *reinterpret_cast<const unsigned int*>(Tg + (size_t)s7 * 128 + co);
        ax += bf2f((unsigned short)w0) + bf2f((unsigned short)w1)
            + bf2f((unsigned short)w2) + bf2f((unsigned short)w3)
            + bf2f((unsigned short)w4) + bf2f((unsigned short)w5)
            + bf2f((unsigned short)w6) + bf2f((unsigned short)w7);
        ay += bf2f((unsigned short)(w0 >> 16)) + bf2f((unsigned short)(w1 >> 16))
            + bf2f((unsigned short)(w2 >> 16)) + bf2f((unsigned short)(w3 >> 16))
            + bf2f((unsigned short)(w4 >> 16)) + bf2f((unsigned short)(w5 >> 16))
            + bf2f((unsigned short)(w6 >> 16)) + bf2f((unsigned short)(w7 >> 16));
    }
    for (; i + 3 < o1; i += 4) {
        int s0 = csr[i], s1 = csr[i + 1], s2 = csr[i + 2], s3 = csr[i + 3];
        unsigned int w0 = *reinterpret_cast<const unsigned int*>(Tg + (size_t)s0 * 128 + co);
        unsigned int w1 = *reinterpret_cast<const unsigned int*>(Tg + (size_t)s1 * 128 + co);
        unsigned int w2 = *reinterpret_cast<const unsigned int*>(Tg + (size_t)s2 * 128 + co);
        unsigned int w3 = *reinterpret_cast<const unsigned int*>(Tg + (size_t)s3 * 128 + co);
        ax += bf2f((unsigned short)w0) + bf2f((unsigned short)w1)
            + bf2f((unsigned short)w2) + bf2f((unsigned short)w3);
        ay += bf2f((unsigned short)(w0 >> 16)) + bf2f((unsigned short)(w1 >> 16))
            + bf2f((unsigned short)(w2 >> 16)) + bf2f((unsigned short)(w3 >> 16));
    }
    for (; i < o1; ++i) {
        int s = csr[i];
        unsigned int w = *reinterpret_cast<const unsigned int*>(Tg + (size_t)s * 128 + co);
        ax += bf2f((unsigned short)w);
        ay += bf2f((unsigned short)(w >> 16));
    }
    int deg = o1 - o0;
    float sc = (deg > 0) ? 1.0f / (float)deg : 0.0f;
    unsigned int outw = (unsigned int)f2bf(ax * sc) | ((unsigned int)f2bf(ay * sc) << 16);
    *reinterpret_cast<unsigned int*>(outp + co) = outw;
}

// ---------------------------------------------------------------------------
// MFMA finish (round-6 structure), head from d_out (stride 256, in-place
// row-aliased: bf16[r][256] == fp32[r][128] bytes; wave stores depend on all
// its loads; waves own disjoint rows), tail from compact self table Ts.
// ---------------------------------------------------------------------------
#define NB_FIN 782   // ceil(50000/64)

__global__ __launch_bounds__(256) void finish2c_kernel(
    unsigned short* dout_u16,
    const unsigned short* __restrict__ T_user, const unsigned short* __restrict__ T_item,
    const unsigned short* __restrict__ WfragUI, const unsigned short* __restrict__ WfragIU,
    const float* __restrict__ b_ui, const float* __restrict__ b_iu)
{
    const int b = blockIdx.x;
    const unsigned short *headBase, *Ts, *Wfrag;
    const float* bias;
    float* outp;
    int rowBase;
    if (b < NB_FIN) {
        headBase = dout_u16 + (size_t)N_USER * 256;
        Ts = T_item; Wfrag = WfragUI; bias = b_ui;
        outp = reinterpret_cast<float*>(dout_u16) + (size_t)N_USER * 128;
        rowBase = b * 64;
    } else {
        headBase = dout_u16;
        Ts = T_user; Wfrag = WfragIU; bias = b_iu;
        outp = reinterpret_cast<float*>(dout_u16);
        rowBase = (b - NB_FIN) * 64;
    }

    const int tid  = threadIdx.x;
    const int wave = tid >> 6;
    const int lane = tid & 63;
    const int kg   = lane >> 4;
    rowBase += wave * 16;

    int arow = rowBase + (lane & 15);
    int arow_c = (arow < 50000) ? arow : 49999;
    const unsigned short* head_ptr = headBase + (size_t)arow_c * 256 + kg * 8;
    const unsigned short* tail_ptr = Ts + (size_t)arow_c * 128 + kg * 8;

    f32x4 acc[8];
#pragma unroll
    for (int c = 0; c < 8; ++c) acc[c] = (f32x4){0.f, 0.f, 0.f, 0.f};

#pragma unroll
    for (int ks = 0; ks < 8; ++ks) {
        bf16x8 a;
        if (ks < 4) a = *reinterpret_cast<const bf16x8*>(head_ptr + ks * 32);       // agg (Wl)
        else        a = *reinterpret_cast<const bf16x8*>(tail_ptr + (ks - 4) * 32); // self (Wr)
        const unsigned short* bptr = Wfrag + ((size_t)(ks * 8) * 64 + lane) * 8;
#pragma unroll
        for (int c = 0; c < 8; ++c) {
            bf16x8 bb = *reinterpret_cast<const bf16x8*>(bptr + (size_t)c * 512);
            acc[c] = __builtin_amdgcn_mfma_f32_16x16x32_bf16(a, bb, acc[c], 0, 0, 0);
        }
    }

    const int orow0 = rowBase + kg * 4;
    const int ocol  = lane & 15;
#pragma unroll
    for (int c = 0; c < 8; ++c) {
        float bv = bias[c * 16 + ocol];
#pragma unroll
        for (int r = 0; r < 4; ++r) {
            int row = orow0 + r;
            if (row < 50000) outp[(size_t)row * 128 + c * 16 + ocol] = acc[c][r] + bv;
        }
    }
}

// ---------------------------------------------------------------------------
extern "C" void kernel_launch(void* const* d_in, const int* in_sizes, int n_in,
                              void* d_out, int out_size, void* d_ws, size_t ws_size,
                              hipStream_t stream) {
    const int*   user_ids = (const int*)d_in[0];
    const float* item_x   = (const float*)d_in[1];
    const int*   edge_ui  = (const int*)d_in[2];
    const int*   edge_iu  = (const int*)d_in[3];
    const float* user_emb = (const float*)d_in[4];
    const float* W_l_ui   = (const float*)d_in[5];
    const float* W_r_ui   = (const float*)d_in[6];
    const float* b_ui     = (const float*)d_in[7];
    const float* W_l_iu   = (const float*)d_in[8];
    const float* W_r_iu   = (const float*)d_in[9];
    const float* b_iu     = (const float*)d_in[10];

    unsigned short* dout_u16 = (unsigned short*)d_out;

    // Workspace (16B-aligned blocks first)
    unsigned short* WfragUI = (unsigned short*)d_ws;            // 32768 u16
    unsigned short* WfragIU = WfragUI + 32768;                  // 32768 u16
    unsigned short* T_user  = WfragIU + 32768;                  // 50000*128 u16 (12.8MB)
    unsigned short* T_item  = T_user + (size_t)N_USER * 128;    // 12.8MB
    unsigned int*   records = (unsigned int*)(T_item + (size_t)N_ITEM * 128);  // NE2 (6.4MB)
    unsigned short* csr     = (unsigned short*)(records + NE2); // NE2 (3.2MB)
    int* gcnt  = (int*)(csr + NE2);                             // NBKT
    int* bbase = gcnt + NBKT;                                   // NBKT+1
    int* bcur  = bbase + NBKT + 1;                              // NBKT
    int* off   = bcur + NBKT;                                   // NTOT+1

    hipMemsetAsync(gcnt, 0, NBKT * sizeof(int), stream);

    mega3_kernel<<<PACKA_BLOCKS + PACKW_BLOCKS + CNT_BLOCKS, 256, 0, stream>>>(
        user_emb, user_ids, item_x, edge_ui, edge_iu,
        W_l_ui, W_r_ui, W_l_iu, W_r_iu,
        T_user, T_item, WfragUI, WfragIU, gcnt);
    bucketscan_kernel<<<1, 256, 0, stream>>>(gcnt, bbase, bcur);
    scatter_records_kernel<<<B2_BLOCKS, 1024, 0, stream>>>(edge_ui, edge_iu, bcur, records);
    csr_build_kernel<<<NBKT, 1024, 0, stream>>>(records, bbase, csr, off);

    agg2c_kernel<<<(NTOT * 64) / 256, 256, 0, stream>>>(T_user, T_item, off, csr, dout_u16);
    finish2c_kernel<<<2 * NB_FIN, 256, 0, stream>>>(
        dout_u16, T_user, T_item, WfragUI, WfragIU, b_ui, b_iu);
}

// Round 16
// 140.963 us; speedup vs baseline: 2.0328x; 1.0420x over previous
//
#include <hip/hip_runtime.h>

#define N_USER 50000
#define N_ITEM 50000
#define N_EDGE 800000
#define D 128
#define NTOT   100000          // combined dst space: [0,50K)=items, [50K,100K)=users
#define NE2    1600000         // both directions' edges
#define BKT_SH 9               // 512 dsts per bucket
#define NBKT   196             // ceil(NTOT / 512)
#define CAP    12288           // LDS csr staging cap (bucket mean 8192, sigma ~90)

typedef __attribute__((ext_vector_type(8))) short     bf16x8;
typedef __attribute__((ext_vector_type(4))) float     f32x4;
typedef __attribute__((ext_vector_type(4))) unsigned short ushortx4;
typedef __attribute__((ext_vector_type(8))) unsigned short ushortx8;

__device__ __forceinline__ unsigned short f2bf(float f) {
    unsigned int u = __float_as_uint(f);
    unsigned int r = (u + 0x7fffu + ((u >> 16) & 1u)) >> 16;   // RNE
    return (unsigned short)r;
}
__device__ __forceinline__ float bf2f(unsigned short b) {
    return __uint_as_float(((unsigned int)b) << 16);
}

// ---------------------------------------------------------------------------
// MEGA kernel (block-range roles, all 256 thr). pack/packW/count are mutually
// independent -> count's latency hides under pack's copy traffic.
// ---------------------------------------------------------------------------
#define PACKA_BLOCKS 12500
#define PACKW_BLOCKS 32
#define CNT_BLOCKS   391   // ceil(NE2 / 4096)

__global__ __launch_bounds__(256) void mega3_kernel(
    const float* __restrict__ user_emb, const int* __restrict__ user_ids,
    const float* __restrict__ item_x,
    const int* __restrict__ edge_ui, const int* __restrict__ edge_iu,
    const float* __restrict__ Wl_ui, const float* __restrict__ Wr_ui,
    const float* __restrict__ Wl_iu, const float* __restrict__ Wr_iu,
    unsigned short* T_user, unsigned short* T_item,
    unsigned short* WfragUI, unsigned short* WfragIU,
    int* __restrict__ gcnt)
{
    const int b = blockIdx.x;
    const int tid = threadIdx.x;

    if (b < PACKA_BLOCKS) {
        int gid = b * 256 + tid;
        int row = gid >> 5;
        int c = (gid & 31) << 2;
        const float* src;
        unsigned short* dst;
        if (row < N_USER) {
            src = user_emb + (size_t)user_ids[row] * D;
            dst = T_user + (size_t)row * 128;
        } else {
            int r = row - N_USER;
            src = item_x + (size_t)r * D;
            dst = T_item + (size_t)r * 128;
        }
        const float4 v = *reinterpret_cast<const float4*>(src + c);
        ushortx4 o;
        o.x = f2bf(v.x); o.y = f2bf(v.y); o.z = f2bf(v.z); o.w = f2bf(v.w);
        *reinterpret_cast<ushortx4*>(dst + c) = o;
    } else if (b < PACKA_BLOCKS + PACKW_BLOCKS) {
        int id = (b - PACKA_BLOCKS) * 256 + tid;   // [0, 8192)
        const float *Wl, *Wr;
        unsigned short* Wf;
        if (id < 4096) { Wl = Wl_ui; Wr = Wr_ui; Wf = WfragUI; }
        else { id -= 4096; Wl = Wl_iu; Wr = Wr_iu; Wf = WfragIU; }
        int lane = id & 63;
        int c    = (id >> 6) & 7;
        int ks   = id >> 9;
        int col  = c * 16 + (lane & 15);
        int k0   = ks * 32 + (lane >> 4) * 8;
        ushortx8 o;
#pragma unroll
        for (int i = 0; i < 8; ++i) {
            int k = k0 + i;
            float f = (k < D) ? Wl[(size_t)k * D + col] : Wr[(size_t)(k - D) * D + col];
            o[i] = f2bf(f);
        }
        *reinterpret_cast<ushortx8*>(Wf + (size_t)id * 8) = o;
    } else {
        __shared__ int bcnt[NBKT];
        for (int i = tid; i < NBKT; i += 256) bcnt[i] = 0;
        __syncthreads();
        int e0 = (b - PACKA_BLOCKS - PACKW_BLOCKS) * 4096;
#pragma unroll
        for (int j = 0; j < 16; ++j) {
            int e = e0 + j * 256 + tid;
            if (e < NE2) {
                int d = (e < N_EDGE) ? edge_ui[N_EDGE + e]
                                     : (N_ITEM + edge_iu[N_EDGE + (e - N_EDGE)]);
                atomicAdd(&bcnt[d >> BKT_SH], 1);
            }
        }
        __syncthreads();
        for (int i = tid; i < NBKT; i += 256)
            if (bcnt[i]) atomicAdd(&gcnt[i], bcnt[i]);
    }
}

// ---------------------------------------------------------------------------
// Scan 196 bucket counts -> bucket bases; init bucket cursors.
// ---------------------------------------------------------------------------
__global__ __launch_bounds__(256) void bucketscan_kernel(
    const int* __restrict__ gcnt, int* __restrict__ bbase, int* __restrict__ bcur)
{
    __shared__ int s[256];
    int tid = threadIdx.x;
    int v = (tid < NBKT) ? gcnt[tid] : 0;
    s[tid] = v;
    __syncthreads();
    for (int d = 1; d < 256; d <<= 1) {
        int t = (tid >= d) ? s[tid - d] : 0;
        __syncthreads();
        s[tid] += t;
        __syncthreads();
    }
    if (tid < NBKT) {
        int base = s[tid] - v;     // exclusive
        bbase[tid] = base;
        bcur[tid]  = base;
    }
    if (tid == NBKT - 1) bbase[NBKT] = s[tid];
}

// ---------------------------------------------------------------------------
// Scatter records into bucket-segmented array. Record = src16 | dstlow9<<16.
// Rank captured from the pass-1 count atomic; final writes atomic-free.
// ---------------------------------------------------------------------------
#define B2_BLOCKS 196   // ceil(NE2 / 8192)

__global__ __launch_bounds__(1024) void scatter_records_kernel(
    const int* __restrict__ edge_ui, const int* __restrict__ edge_iu,
    int* __restrict__ bcur, unsigned int* __restrict__ records)
{
    __shared__ int bcnt[NBKT];
    __shared__ int bpos[NBKT];
    const int tid = threadIdx.x;
    for (int i = tid; i < NBKT; i += 1024) bcnt[i] = 0;
    __syncthreads();

    const int e0 = blockIdx.x * 8192;
    unsigned int rec[8];
    int bkt[8], rnk[8];
#pragma unroll
    for (int j = 0; j < 8; ++j) {
        int e = e0 + j * 1024 + tid;
        bkt[j] = -1;
        if (e < NE2) {
            int s, d;
            if (e < N_EDGE) { s = edge_ui[e]; d = edge_ui[N_EDGE + e]; }
            else { int f = e - N_EDGE; s = edge_iu[f]; d = N_ITEM + edge_iu[N_EDGE + f]; }
            bkt[j] = d >> BKT_SH;
            rec[j] = (unsigned int)s | ((unsigned int)(d & 511) << 16);
            rnk[j] = atomicAdd(&bcnt[bkt[j]], 1);
        }
    }
    __syncthreads();
    for (int i = tid; i < NBKT; i += 1024) {
        int c = bcnt[i];
        bpos[i] = c ? atomicAdd(&bcur[i], c) : 0;
    }
    __syncthreads();
#pragma unroll
    for (int j = 0; j < 8; ++j) {
        if (bkt[j] >= 0) records[bpos[bkt[j]] + rnk[j]] = rec[j];
    }
}

// ---------------------------------------------------------------------------
// Per-bucket CSR build: LDS counting-sort by dst within the bucket; emits off[].
// ---------------------------------------------------------------------------
__global__ __launch_bounds__(1024) void csr_build_kernel(
    const unsigned int* __restrict__ records, const int* __restrict__ bbase,
    unsigned short* __restrict__ csr, int* __restrict__ off)
{
    __shared__ int dcnt[512];
    __shared__ int sa[512], sb[512];
    __shared__ int dcur[512];
    __shared__ unsigned short stage[CAP];

    const int b    = blockIdx.x;
    const int tid  = threadIdx.x;
    const int base = bbase[b];
    const int nb   = bbase[b + 1] - base;

    if (tid < 512) dcnt[tid] = 0;
    __syncthreads();

    for (int i = tid; i < nb; i += 1024)
        atomicAdd(&dcnt[records[base + i] >> 16], 1);
    __syncthreads();

    int* pa = sa; int* pb = sb;
    if (tid < 512) pa[tid] = dcnt[tid];
    __syncthreads();
    for (int d = 1; d < 512; d <<= 1) {
        if (tid < 512) pb[tid] = pa[tid] + ((tid >= d) ? pa[tid - d] : 0);
        __syncthreads();
        int* t = pa; pa = pb; pb = t;
    }
    if (tid < 512) {
        int excl = pa[tid] - dcnt[tid];
        dcur[tid] = excl;
        int dst = b * 512 + tid;
        if (dst < NTOT) off[dst] = base + excl;
    }
    if (b == NBKT - 1 && tid == 0) off[NTOT] = NE2;
    __syncthreads();

    if (nb <= CAP) {
        for (int i = tid; i < nb; i += 1024) {
            unsigned int r = records[base + i];
            int p = atomicAdd(&dcur[r >> 16], 1);
            stage[p] = (unsigned short)r;
        }
        __syncthreads();
        for (int i = tid; i < nb; i += 1024) csr[base + i] = stage[i];
    } else {
        for (int i = tid; i < nb; i += 1024) {
            unsigned int r = records[base + i];
            int p = atomicAdd(&dcur[r >> 16], 1);
            csr[base + p] = (unsigned short)r;
        }
    }
}

// ---------------------------------------------------------------------------
// Aggregate (mean), CHUNK+READLANE gather: 256 thr = 4 free-running waves,
// one wave per dst row, lane owns dims [2l,2l+1].
// csr indices come from ONE lane-cooperative 32B chunk load (lanes 0-15 hold
// csr[i..i+15]) distributed via v_readlane -> SGPR src -> scalar-based
// gather addressing. 16 gathers in flight; tail handled from the same chunk
// with 8/4/2/1 unrolled levels (csr padded by 16 entries).
// Writes bf16 mean into d_out head halves (stride 256).
// ---------------------------------------------------------------------------
__global__ __launch_bounds__(256) void agg2c_kernel(
    const unsigned short* __restrict__ T_user, const unsigned short* __restrict__ T_item,
    const int* __restrict__ off, const unsigned short* __restrict__ csr,
    unsigned short* __restrict__ dout_u16)
{
    int r = (blockIdx.x * blockDim.x + threadIdx.x) >> 6;
    if (r >= NTOT) return;
    const int lane = threadIdx.x & 63;
    const unsigned short* Tg;
    unsigned short* outp;
    if (r < N_ITEM) { Tg = T_user; outp = dout_u16 + (size_t)(N_USER + r) * 256; }
    else            { Tg = T_item; outp = dout_u16 + (size_t)(r - N_ITEM) * 256; }

    const int o0 = off[r], o1 = off[r + 1];
    const int co = lane * 2;
    float ax = 0.f, ay = 0.f;
    int i = o0;

    // main: 16 edges per chunk, all gathers independent, srcs in SGPRs
    for (; i + 15 < o1; i += 16) {
        int cv = csr[i + (lane & 15)];
        unsigned int w[16];
#pragma unroll
        for (int p = 0; p < 16; ++p) {
            int s = __builtin_amdgcn_readlane(cv, p);
            w[p] = *reinterpret_cast<const unsigned int*>(Tg + (size_t)s * 128 + co);
        }
#pragma unroll
        for (int p = 0; p < 16; ++p) {
            ax += bf2f((unsigned short)w[p]);
            ay += bf2f((unsigned short)(w[p] >> 16));
        }
    }

    // tail: one chunk load (csr padded by 16), 8/4/2/1 parallel levels
    int rem = o1 - i;
    if (rem > 0) {
        int cv = csr[i + (lane & 15)];
        int bl = 0;   // consumed lanes within chunk (uniform)
        if (rem >= 8) {
            unsigned int w[8];
#pragma unroll
            for (int p = 0; p < 8; ++p) {
                int s = __builtin_amdgcn_readlane(cv, p);
                w[p] = *reinterpret_cast<const unsigned int*>(Tg + (size_t)s * 128 + co);
            }
#pragma unroll
            for (int p = 0; p < 8; ++p) {
                ax += bf2f((unsigned short)w[p]);
                ay += bf2f((unsigned short)(w[p] >> 16));
            }
            bl = 8; rem -= 8;
        }
        if (rem >= 4) {
            unsigned int w[4];
#pragma unroll
            for (int p = 0; p < 4; ++p) {
                int s = __builtin_amdgcn_readlane(cv, bl + p);
                w[p] = *reinterpret_cast<const unsigned int*>(Tg + (size_t)s * 128 + co);
            }
#pragma unroll
            for (int p = 0; p < 4; ++p) {
                ax += bf2f((unsigned short)w[p]);
                ay += bf2f((unsigned short)(w[p] >> 16));
            }
            bl += 4; rem -= 4;
        }
        if (rem >= 2) {
            int s0 = __builtin_amdgcn_readlane(cv, bl);
            int s1 = __builtin_amdgcn_readlane(cv, bl + 1);
            unsigned int w0 = *reinterpret_cast<const unsigned int*>(Tg + (size_t)s0 * 128 + co);
            unsigned int w1 = *reinterpret_cast<const unsigned int*>(Tg + (size_t)s1 * 128 + co);
            ax += bf2f((unsigned short)w0) + bf2f((unsigned short)w1);
            ay += bf2f((unsigned short)(w0 >> 16)) + bf2f((unsigned short)(w1 >> 16));
            bl += 2; rem -= 2;
        }
        if (rem >= 1) {
            int s = __builtin_amdgcn_readlane(cv, bl);
            unsigned int w = *reinterpret_cast<const unsigned int*>(Tg + (size_t)s * 128 + co);
            ax += bf2f((unsigned short)w);
            ay += bf2f((unsigned short)(w >> 16));
        }
    }

    int deg = o1 - o0;
    float sc = (deg > 0) ? 1.0f / (float)deg : 0.0f;
    unsigned int outw = (unsigned int)f2bf(ax * sc) | ((unsigned int)f2bf(ay * sc) << 16);
    *reinterpret_cast<unsigned int*>(outp + co) = outw;
}

// ---------------------------------------------------------------------------
// MFMA finish (round-6 structure), head from d_out (stride 256, in-place
// row-aliased: bf16[r][256] == fp32[r][128] bytes; wave stores depend on all
// its loads; waves own disjoint rows), tail from compact self table Ts.
// ---------------------------------------------------------------------------
#define NB_FIN 782   // ceil(50000/64)

__global__ __launch_bounds__(256) void finish2c_kernel(
    unsigned short* dout_u16,
    const unsigned short* __restrict__ T_user, const unsigned short* __restrict__ T_item,
    const unsigned short* __restrict__ WfragUI, const unsigned short* __restrict__ WfragIU,
    const float* __restrict__ b_ui, const float* __restrict__ b_iu)
{
    const int b = blockIdx.x;
    const unsigned short *headBase, *Ts, *Wfrag;
    const float* bias;
    float* outp;
    int rowBase;
    if (b < NB_FIN) {
        headBase = dout_u16 + (size_t)N_USER * 256;
        Ts = T_item; Wfrag = WfragUI; bias = b_ui;
        outp = reinterpret_cast<float*>(dout_u16) + (size_t)N_USER * 128;
        rowBase = b * 64;
    } else {
        headBase = dout_u16;
        Ts = T_user; Wfrag = WfragIU; bias = b_iu;
        outp = reinterpret_cast<float*>(dout_u16);
        rowBase = (b - NB_FIN) * 64;
    }

    const int tid  = threadIdx.x;
    const int wave = tid >> 6;
    const int lane = tid & 63;
    const int kg   = lane >> 4;
    rowBase += wave * 16;

    int arow = rowBase + (lane & 15);
    int arow_c = (arow < 50000) ? arow : 49999;
    const unsigned short* head_ptr = headBase + (size_t)arow_c * 256 + kg * 8;
    const unsigned short* tail_ptr = Ts + (size_t)arow_c * 128 + kg * 8;

    f32x4 acc[8];
#pragma unroll
    for (int c = 0; c < 8; ++c) acc[c] = (f32x4){0.f, 0.f, 0.f, 0.f};

#pragma unroll
    for (int ks = 0; ks < 8; ++ks) {
        bf16x8 a;
        if (ks < 4) a = *reinterpret_cast<const bf16x8*>(head_ptr + ks * 32);       // agg (Wl)
        else        a = *reinterpret_cast<const bf16x8*>(tail_ptr + (ks - 4) * 32); // self (Wr)
        const unsigned short* bptr = Wfrag + ((size_t)(ks * 8) * 64 + lane) * 8;
#pragma unroll
        for (int c = 0; c < 8; ++c) {
            bf16x8 bb = *reinterpret_cast<const bf16x8*>(bptr + (size_t)c * 512);
            acc[c] = __builtin_amdgcn_mfma_f32_16x16x32_bf16(a, bb, acc[c], 0, 0, 0);
        }
    }

    const int orow0 = rowBase + kg * 4;
    const int ocol  = lane & 15;
#pragma unroll
    for (int c = 0; c < 8; ++c) {
        float bv = bias[c * 16 + ocol];
#pragma unroll
        for (int r = 0; r < 4; ++r) {
            int row = orow0 + r;
            if (row < 50000) outp[(size_t)row * 128 + c * 16 + ocol] = acc[c][r] + bv;
        }
    }
}

// ---------------------------------------------------------------------------
extern "C" void kernel_launch(void* const* d_in, const int* in_sizes, int n_in,
                              void* d_out, int out_size, void* d_ws, size_t ws_size,
                              hipStream_t stream) {
    const int*   user_ids = (const int*)d_in[0];
    const float* item_x   = (const float*)d_in[1];
    const int*   edge_ui  = (const int*)d_in[2];
    const int*   edge_iu  = (const int*)d_in[3];
    const float* user_emb = (const float*)d_in[4];
    const float* W_l_ui   = (const float*)d_in[5];
    const float* W_r_ui   = (const float*)d_in[6];
    const float* b_ui     = (const float*)d_in[7];
    const float* W_l_iu   = (const float*)d_in[8];
    const float* W_r_iu   = (const float*)d_in[9];
    const float* b_iu     = (const float*)d_in[10];

    unsigned short* dout_u16 = (unsigned short*)d_out;

    // Workspace (16B-aligned blocks first)
    unsigned short* WfragUI = (unsigned short*)d_ws;            // 32768 u16
    unsigned short* WfragIU = WfragUI + 32768;                  // 32768 u16
    unsigned short* T_user  = WfragIU + 32768;                  // 50000*128 u16 (12.8MB)
    unsigned short* T_item  = T_user + (size_t)N_USER * 128;    // 12.8MB
    unsigned int*   records = (unsigned int*)(T_item + (size_t)N_ITEM * 128);  // NE2 (6.4MB)
    unsigned short* csr     = (unsigned short*)(records + NE2); // NE2 + 16 pad (3.2MB)
    int* gcnt  = (int*)(csr + NE2 + 16);                        // NBKT
    int* bbase = gcnt + NBKT;                                   // NBKT+1
    int* bcur  = bbase + NBKT + 1;                              // NBKT
    int* off   = bcur + NBKT;                                   // NTOT+1

    hipMemsetAsync(gcnt, 0, NBKT * sizeof(int), stream);

    mega3_kernel<<<PACKA_BLOCKS + PACKW_BLOCKS + CNT_BLOCKS, 256, 0, stream>>>(
        user_emb, user_ids, item_x, edge_ui, edge_iu,
        W_l_ui, W_r_ui, W_l_iu, W_r_iu,
        T_user, T_item, WfragUI, WfragIU, gcnt);
    bucketscan_kernel<<<1, 256, 0, stream>>>(gcnt, bbase, bcur);
    scatter_records_kernel<<<B2_BLOCKS, 1024, 0, stream>>>(edge_ui, edge_iu, bcur, records);
    csr_build_kernel<<<NBKT, 1024, 0, stream>>>(records, bbase, csr, off);

    agg2c_kernel<<<(NTOT * 64) / 256, 256, 0, stream>>>(T_user, T_item, off, csr, dout_u16);
    finish2c_kernel<<<2 * NB_FIN, 256, 0, stream>>>(
        dout_u16, T_user, T_item, WfragUI, WfragIU, b_ui, b_iu);
}

// Round 17
// 121.710 us; speedup vs baseline: 2.3543x; 1.1582x over previous
//
#include <hip/hip_runtime.h>

#define N_USER 50000
#define N_ITEM 50000
#define N_EDGE 800000
#define D 128
#define NTOT   100000          // combined dst space: [0,50K)=items, [50K,100K)=users
#define NE2    1600000         // both directions' edges
#define BKT_SH 9               // 512 dsts per bucket
#define NBKT   196             // ceil(NTOT / 512)
#define CAP    12288           // LDS csr staging cap
#define SLOT   10240           // fixed per-bucket segment (mean 8192, sigma ~90 -> 22 sigma slack)

typedef __attribute__((ext_vector_type(8))) short     bf16x8;
typedef __attribute__((ext_vector_type(4))) float     f32x4;
typedef __attribute__((ext_vector_type(4))) unsigned short ushortx4;
typedef __attribute__((ext_vector_type(8))) unsigned short ushortx8;

__device__ __forceinline__ unsigned short f2bf(float f) {
    unsigned int u = __float_as_uint(f);
    unsigned int r = (u + 0x7fffu + ((u >> 16) & 1u)) >> 16;   // RNE
    return (unsigned short)r;
}
__device__ __forceinline__ float bf2f(unsigned short b) {
    return __uint_as_float(((unsigned int)b) << 16);
}

// ---------------------------------------------------------------------------
// SCATTER + PACK mega-kernel (1024 thr blocks).
//  [0, 196)        scatter: records into STATIC bucket slots (base = bkt*SLOT,
//                  relative cursor in bcur[], rank-captured, atomic-free store)
//  [196, 3321)     pack features -> compact bf16 tables (32 rows/block)
//  [3321, 3329)    pack W frags (2 x 4096 ids)
// Record = src16 | dstlow9<<16. Scatter blocks first so they start while the
// pack blocks keep the machine busy (mutual latency hiding).
// ---------------------------------------------------------------------------
#define SCAT_BLOCKS  196    // ceil(NE2 / 8192)
#define PACK_BLOCKS  3125   // 100000 rows * 32 lanes / 1024
#define PACKW_BLOCKS 8      // 8192 ids / 1024

__global__ __launch_bounds__(1024) void scatterpack_kernel(
    const float* __restrict__ user_emb, const int* __restrict__ user_ids,
    const float* __restrict__ item_x,
    const int* __restrict__ edge_ui, const int* __restrict__ edge_iu,
    const float* __restrict__ Wl_ui, const float* __restrict__ Wr_ui,
    const float* __restrict__ Wl_iu, const float* __restrict__ Wr_iu,
    unsigned short* T_user, unsigned short* T_item,
    unsigned short* WfragUI, unsigned short* WfragIU,
    int* __restrict__ bcur, unsigned int* __restrict__ records)
{
    const int b = blockIdx.x;
    const int tid = threadIdx.x;

    if (b < SCAT_BLOCKS) {
        __shared__ int bcnt[NBKT];
        __shared__ int bpos[NBKT];
        for (int i = tid; i < NBKT; i += 1024) bcnt[i] = 0;
        __syncthreads();

        const int e0 = b * 8192;
        unsigned int rec[8];
        int bkt[8], rnk[8];
#pragma unroll
        for (int j = 0; j < 8; ++j) {
            int e = e0 + j * 1024 + tid;
            bkt[j] = -1;
            if (e < NE2) {
                int s, d;
                if (e < N_EDGE) { s = edge_ui[e]; d = edge_ui[N_EDGE + e]; }
                else { int f = e - N_EDGE; s = edge_iu[f]; d = N_ITEM + edge_iu[N_EDGE + f]; }
                bkt[j] = d >> BKT_SH;
                rec[j] = (unsigned int)s | ((unsigned int)(d & 511) << 16);
                rnk[j] = atomicAdd(&bcnt[bkt[j]], 1);
            }
        }
        __syncthreads();
        for (int i = tid; i < NBKT; i += 1024) {
            int c = bcnt[i];
            bpos[i] = i * SLOT + (c ? atomicAdd(&bcur[i], c) : 0);
        }
        __syncthreads();
#pragma unroll
        for (int j = 0; j < 8; ++j) {
            if (bkt[j] >= 0) {
                int p = bpos[bkt[j]] + rnk[j];
                if (p < (bkt[j] + 1) * SLOT) records[p] = rec[j];   // slot-bound guard
            }
        }
    } else if (b < SCAT_BLOCKS + PACK_BLOCKS) {
        int gid = (b - SCAT_BLOCKS) * 1024 + tid;   // [0, 3.2M)
        int row = gid >> 5;                         // [0, 100000) exactly
        int c = (gid & 31) << 2;
        const float* src;
        unsigned short* dst;
        if (row < N_USER) {
            src = user_emb + (size_t)user_ids[row] * D;
            dst = T_user + (size_t)row * 128;
        } else {
            int r = row - N_USER;
            src = item_x + (size_t)r * D;
            dst = T_item + (size_t)r * 128;
        }
        const float4 v = *reinterpret_cast<const float4*>(src + c);
        ushortx4 o;
        o.x = f2bf(v.x); o.y = f2bf(v.y); o.z = f2bf(v.z); o.w = f2bf(v.w);
        *reinterpret_cast<ushortx4*>(dst + c) = o;
    } else {
        int id = (b - SCAT_BLOCKS - PACK_BLOCKS) * 1024 + tid;   // [0, 8192)
        const float *Wl, *Wr;
        unsigned short* Wf;
        if (id < 4096) { Wl = Wl_ui; Wr = Wr_ui; Wf = WfragUI; }
        else { id -= 4096; Wl = Wl_iu; Wr = Wr_iu; Wf = WfragIU; }
        int lane = id & 63;
        int c    = (id >> 6) & 7;
        int ks   = id >> 9;
        int col  = c * 16 + (lane & 15);
        int k0   = ks * 32 + (lane >> 4) * 8;
        ushortx8 o;
#pragma unroll
        for (int i = 0; i < 8; ++i) {
            int k = k0 + i;
            float f = (k < D) ? Wl[(size_t)k * D + col] : Wr[(size_t)(k - D) * D + col];
            o[i] = f2bf(f);
        }
        *reinterpret_cast<ushortx8*>(Wf + (size_t)id * 8) = o;
    }
}

// ---------------------------------------------------------------------------
// Per-bucket CSR build in static slots: LDS counting-sort by dst within the
// bucket; emits offdeg[dst] = (global csr offset, degree) as uint2.
// ---------------------------------------------------------------------------
__global__ __launch_bounds__(1024) void csr_build_kernel(
    const unsigned int* __restrict__ records, const int* __restrict__ bcur,
    unsigned short* __restrict__ csr, uint2* __restrict__ offdeg)
{
    __shared__ int dcnt[512];
    __shared__ int sa[512], sb[512];
    __shared__ int dcur[512];
    __shared__ unsigned short stage[CAP];

    const int b    = blockIdx.x;
    const int tid  = threadIdx.x;
    const int base = b * SLOT;
    int nb = bcur[b];
    if (nb > SLOT) nb = SLOT;

    if (tid < 512) dcnt[tid] = 0;
    __syncthreads();

    for (int i = tid; i < nb; i += 1024)
        atomicAdd(&dcnt[records[base + i] >> 16], 1);
    __syncthreads();

    int* pa = sa; int* pb = sb;
    if (tid < 512) pa[tid] = dcnt[tid];
    __syncthreads();
    for (int d = 1; d < 512; d <<= 1) {
        if (tid < 512) pb[tid] = pa[tid] + ((tid >= d) ? pa[tid - d] : 0);
        __syncthreads();
        int* t = pa; pa = pb; pb = t;
    }
    if (tid < 512) {
        int excl = pa[tid] - dcnt[tid];
        dcur[tid] = excl;
        int dst = b * 512 + tid;
        if (dst < NTOT) offdeg[dst] = make_uint2((unsigned int)(base + excl),
                                                 (unsigned int)dcnt[tid]);
    }
    __syncthreads();

    if (nb <= CAP) {
        for (int i = tid; i < nb; i += 1024) {
            unsigned int r = records[base + i];
            int p = atomicAdd(&dcur[r >> 16], 1);
            stage[p] = (unsigned short)r;
        }
        __syncthreads();
        for (int i = tid; i < nb; i += 1024) csr[base + i] = stage[i];
    } else {
        for (int i = tid; i < nb; i += 1024) {
            unsigned int r = records[base + i];
            int p = atomicAdd(&dcur[r >> 16], 1);
            csr[base + p] = (unsigned short)r;
        }
    }
}

// ---------------------------------------------------------------------------
// Aggregate (mean), CHUNK+READLANE gather: 256 thr = 4 free-running waves,
// one wave per dst row, lane owns dims [2l,2l+1].
// csr indices from ONE lane-cooperative 32B chunk load distributed via
// v_readlane -> SGPR src -> scalar-based gather addressing; 16 in flight.
// Per-dst extent from offdeg (uint2). Writes bf16 mean into d_out heads.
// ---------------------------------------------------------------------------
__global__ __launch_bounds__(256) void agg2c_kernel(
    const unsigned short* __restrict__ T_user, const unsigned short* __restrict__ T_item,
    const uint2* __restrict__ offdeg, const unsigned short* __restrict__ csr,
    unsigned short* __restrict__ dout_u16)
{
    int r = (blockIdx.x * blockDim.x + threadIdx.x) >> 6;
    if (r >= NTOT) return;
    const int lane = threadIdx.x & 63;
    const unsigned short* Tg;
    unsigned short* outp;
    if (r < N_ITEM) { Tg = T_user; outp = dout_u16 + (size_t)(N_USER + r) * 256; }
    else            { Tg = T_item; outp = dout_u16 + (size_t)(r - N_ITEM) * 256; }

    const uint2 od = offdeg[r];
    const int o0 = (int)od.x;
    const int deg = (int)od.y;
    const int o1 = o0 + deg;
    const int co = lane * 2;
    float ax = 0.f, ay = 0.f;
    int i = o0;

    // main: 16 edges per chunk, all gathers independent, srcs in SGPRs
    for (; i + 15 < o1; i += 16) {
        int cv = csr[i + (lane & 15)];
        unsigned int w[16];
#pragma unroll
        for (int p = 0; p < 16; ++p) {
            int s = __builtin_amdgcn_readlane(cv, p);
            w[p] = *reinterpret_cast<const unsigned int*>(Tg + (size_t)s * 128 + co);
        }
#pragma unroll
        for (int p = 0; p < 16; ++p) {
            ax += bf2f((unsigned short)w[p]);
            ay += bf2f((unsigned short)(w[p] >> 16));
        }
    }

    // tail: one chunk load (csr padded), 8/4/2/1 parallel levels
    int rem = o1 - i;
    if (rem > 0) {
        int cv = csr[i + (lane & 15)];
        int bl = 0;
        if (rem >= 8) {
            unsigned int w[8];
#pragma unroll
            for (int p = 0; p < 8; ++p) {
                int s = __builtin_amdgcn_readlane(cv, p);
                w[p] = *reinterpret_cast<const unsigned int*>(Tg + (size_t)s * 128 + co);
            }
#pragma unroll
            for (int p = 0; p < 8; ++p) {
                ax += bf2f((unsigned short)w[p]);
                ay += bf2f((unsigned short)(w[p] >> 16));
            }
            bl = 8; rem -= 8;
        }
        if (rem >= 4) {
            unsigned int w[4];
#pragma unroll
            for (int p = 0; p < 4; ++p) {
                int s = __builtin_amdgcn_readlane(cv, bl + p);
                w[p] = *reinterpret_cast<const unsigned int*>(Tg + (size_t)s * 128 + co);
            }
#pragma unroll
            for (int p = 0; p < 4; ++p) {
                ax += bf2f((unsigned short)w[p]);
                ay += bf2f((unsigned short)(w[p] >> 16));
            }
            bl += 4; rem -= 4;
        }
        if (rem >= 2) {
            int s0 = __builtin_amdgcn_readlane(cv, bl);
            int s1 = __builtin_amdgcn_readlane(cv, bl + 1);
            unsigned int w0 = *reinterpret_cast<const unsigned int*>(Tg + (size_t)s0 * 128 + co);
            unsigned int w1 = *reinterpret_cast<const unsigned int*>(Tg + (size_t)s1 * 128 + co);
            ax += bf2f((unsigned short)w0) + bf2f((unsigned short)w1);
            ay += bf2f((unsigned short)(w0 >> 16)) + bf2f((unsigned short)(w1 >> 16));
            bl += 2; rem -= 2;
        }
        if (rem >= 1) {
            int s = __builtin_amdgcn_readlane(cv, bl);
            unsigned int w = *reinterpret_cast<const unsigned int*>(Tg + (size_t)s * 128 + co);
            ax += bf2f((unsigned short)w);
            ay += bf2f((unsigned short)(w >> 16));
        }
    }

    float sc = (deg > 0) ? 1.0f / (float)deg : 0.0f;
    unsigned int outw = (unsigned int)f2bf(ax * sc) | ((unsigned int)f2bf(ay * sc) << 16);
    *reinterpret_cast<unsigned int*>(outp + co) = outw;
}

// ---------------------------------------------------------------------------
// MFMA finish (round-6 structure), head from d_out (stride 256, in-place
// row-aliased: bf16[r][256] == fp32[r][128] bytes; wave stores depend on all
// its loads; waves own disjoint rows), tail from compact self table Ts.
// ---------------------------------------------------------------------------
#define NB_FIN 782   // ceil(50000/64)

__global__ __launch_bounds__(256) void finish2c_kernel(
    unsigned short* dout_u16,
    const unsigned short* __restrict__ T_user, const unsigned short* __restrict__ T_item,
    const unsigned short* __restrict__ WfragUI, const unsigned short* __restrict__ WfragIU,
    const float* __restrict__ b_ui, const float* __restrict__ b_iu)
{
    const int b = blockIdx.x;
    const unsigned short *headBase, *Ts, *Wfrag;
    const float* bias;
    float* outp;
    int rowBase;
    if (b < NB_FIN) {
        headBase = dout_u16 + (size_t)N_USER * 256;
        Ts = T_item; Wfrag = WfragUI; bias = b_ui;
        outp = reinterpret_cast<float*>(dout_u16) + (size_t)N_USER * 128;
        rowBase = b * 64;
    } else {
        headBase = dout_u16;
        Ts = T_user; Wfrag = WfragIU; bias = b_iu;
        outp = reinterpret_cast<float*>(dout_u16);
        rowBase = (b - NB_FIN) * 64;
    }

    const int tid  = threadIdx.x;
    const int wave = tid >> 6;
    const int lane = tid & 63;
    const int kg   = lane >> 4;
    rowBase += wave * 16;

    int arow = rowBase + (lane & 15);
    int arow_c = (arow < 50000) ? arow : 49999;
    const unsigned short* head_ptr = headBase + (size_t)arow_c * 256 + kg * 8;
    const unsigned short* tail_ptr = Ts + (size_t)arow_c * 128 + kg * 8;

    f32x4 acc[8];
#pragma unroll
    for (int c = 0; c < 8; ++c) acc[c] = (f32x4){0.f, 0.f, 0.f, 0.f};

#pragma unroll
    for (int ks = 0; ks < 8; ++ks) {
        bf16x8 a;
        if (ks < 4) a = *reinterpret_cast<const bf16x8*>(head_ptr + ks * 32);       // agg (Wl)
        else        a = *reinterpret_cast<const bf16x8*>(tail_ptr + (ks - 4) * 32); // self (Wr)
        const unsigned short* bptr = Wfrag + ((size_t)(ks * 8) * 64 + lane) * 8;
#pragma unroll
        for (int c = 0; c < 8; ++c) {
            bf16x8 bb = *reinterpret_cast<const bf16x8*>(bptr + (size_t)c * 512);
            acc[c] = __builtin_amdgcn_mfma_f32_16x16x32_bf16(a, bb, acc[c], 0, 0, 0);
        }
    }

    const int orow0 = rowBase + kg * 4;
    const int ocol  = lane & 15;
#pragma unroll
    for (int c = 0; c < 8; ++c) {
        float bv = bias[c * 16 + ocol];
#pragma unroll
        for (int r = 0; r < 4; ++r) {
            int row = orow0 + r;
            if (row < 50000) outp[(size_t)row * 128 + c * 16 + ocol] = acc[c][r] + bv;
        }
    }
}

// ---------------------------------------------------------------------------
extern "C" void kernel_launch(void* const* d_in, const int* in_sizes, int n_in,
                              void* d_out, int out_size, void* d_ws, size_t ws_size,
                              hipStream_t stream) {
    const int*   user_ids = (const int*)d_in[0];
    const float* item_x   = (const float*)d_in[1];
    const int*   edge_ui  = (const int*)d_in[2];
    const int*   edge_iu  = (const int*)d_in[3];
    const float* user_emb = (const float*)d_in[4];
    const float* W_l_ui   = (const float*)d_in[5];
    const float* W_r_ui   = (const float*)d_in[6];
    const float* b_ui     = (const float*)d_in[7];
    const float* W_l_iu   = (const float*)d_in[8];
    const float* W_r_iu   = (const float*)d_in[9];
    const float* b_iu     = (const float*)d_in[10];

    unsigned short* dout_u16 = (unsigned short*)d_out;

    // Workspace (16B-aligned blocks first)
    unsigned short* WfragUI = (unsigned short*)d_ws;            // 32768 u16
    unsigned short* WfragIU = WfragUI + 32768;                  // 32768 u16
    unsigned short* T_user  = WfragIU + 32768;                  // 12.8MB
    unsigned short* T_item  = T_user + (size_t)N_USER * 128;    // 12.8MB
    unsigned int*   records = (unsigned int*)(T_item + (size_t)N_ITEM * 128);  // NBKT*SLOT (8.0MB)
    unsigned short* csr     = (unsigned short*)(records + (size_t)NBKT * SLOT); // NBKT*SLOT+16 (4.0MB)
    uint2* offdeg = (uint2*)(csr + (size_t)NBKT * SLOT + 16);   // NTOT (800KB)
    int*   bcur   = (int*)(offdeg + NTOT);                      // NBKT

    hipMemsetAsync(bcur, 0, NBKT * sizeof(int), stream);

    scatterpack_kernel<<<SCAT_BLOCKS + PACK_BLOCKS + PACKW_BLOCKS, 1024, 0, stream>>>(
        user_emb, user_ids, item_x, edge_ui, edge_iu,
        W_l_ui, W_r_ui, W_l_iu, W_r_iu,
        T_user, T_item, WfragUI, WfragIU, bcur, records);
    csr_build_kernel<<<NBKT, 1024, 0, stream>>>(records, bcur, csr, offdeg);
    agg2c_kernel<<<(NTOT * 64) / 256, 256, 0, stream>>>(T_user, T_item, offdeg, csr, dout_u16);
    finish2c_kernel<<<2 * NB_FIN, 256, 0, stream>>>(
        dout_u16, T_user, T_item, WfragUI, WfragIU, b_ui, b_iu);
}